// Round 4
// baseline (1044.958 us; speedup 1.0000x reference)
//
#include <hip/hip_runtime.h>
#include <hip/hip_bf16.h>

#define DIN 128
#define DH 32
#define DOUT 2
#define NPB 128            // nodes per bucket
#define NPB_SHIFT 7
#define NBUK_MAX 1024      // supports n <= 131072 (and src < 2^17 packing)
#define FILL_EDGES 8192    // edges per binning block

// ---------------------------------------------------------------------------
// workspace (~20.8 MB, budget ~26.8 MB):
//   deg    int[n]        in-degree (excl self)
//   dinv   float[n]
//   gcnt   int[NBUK_MAX] per-bucket edge counts
//   gbase  int[NBUK_MAX] exclusive scan (stable)
//   gcur   int[NBUK_MAX] append cursors (mutable copy)
//   binned uint[E]       (dst&127)<<17 | src, grouped by bucket
//   mqc    bf16[n*32]    dinv-scaled layer-1 messages
//   m2q    float2[n]     dinv-scaled layer-2 messages
// ---------------------------------------------------------------------------

__device__ inline unsigned short f2bf(float f) {
    unsigned int u = __float_as_uint(f);
    u = (u + 0x7FFFu + ((u >> 16) & 1u)) >> 16;
    return (unsigned short)u;
}
__device__ inline float bf2f(unsigned short b) {
    return __uint_as_float(((unsigned int)b) << 16);
}

__global__ void zero_kernel(int* __restrict__ deg, int* __restrict__ gcnt, int n, int nbuk) {
    int i = blockIdx.x * blockDim.x + threadIdx.x;
    if (i < n) deg[i] = 0;
    if (i < nbuk) gcnt[i] = 0;
}

// per-node degree (global int atomics) + per-bucket counts (LDS-staged)
__global__ void hist_kernel(const int* __restrict__ dst, int* __restrict__ deg,
                            int* __restrict__ gcnt, int e, int nbuk) {
    __shared__ int lcnt[NBUK_MAX];
    int t = threadIdx.x;
    for (int i = t; i < nbuk; i += 256) lcnt[i] = 0;
    __syncthreads();
    int e0 = blockIdx.x * FILL_EDGES;
    int m = min(FILL_EDGES, e - e0);
    for (int i = t; i < m; i += 256) {
        int d = dst[e0 + i];
        atomicAdd(&deg[d], 1);
        atomicAdd(&lcnt[d >> NPB_SHIFT], 1);
    }
    __syncthreads();
    for (int i = t; i < nbuk; i += 256)
        if (lcnt[i]) atomicAdd(&gcnt[i], lcnt[i]);
}

__global__ void dinv_kernel(const int* __restrict__ deg, float* __restrict__ dinv, int n) {
    int i = blockIdx.x * blockDim.x + threadIdx.x;
    if (i < n) dinv[i] = rsqrtf((float)(deg[i] + 1));
}

// single-block exclusive scan of gcnt[nbuk] -> gbase, gcur
__global__ void scan_kernel(const int* __restrict__ gcnt, int* __restrict__ gbase,
                            int* __restrict__ gcur, int nbuk) {
    __shared__ int sd[256];
    int t = threadIdx.x;
    int v[4], s = 0;
#pragma unroll
    for (int k = 0; k < 4; ++k) {
        int i = 4 * t + k;
        v[k] = (i < nbuk) ? gcnt[i] : 0;
        s += v[k];
    }
    sd[t] = s;
    __syncthreads();
    for (int off = 1; off < 256; off <<= 1) {
        int x = (t >= off) ? sd[t - off] : 0;
        __syncthreads();
        sd[t] += x;
        __syncthreads();
    }
    int run = sd[t] - s;
#pragma unroll
    for (int k = 0; k < 4; ++k) {
        int i = 4 * t + k;
        if (i < nbuk) { gbase[i] = run; gcur[i] = run; }
        run += v[k];
    }
}

// LDS counting-sort of 8192 edges by bucket, bulk-append to global regions
__global__ void binfill_kernel(const int* __restrict__ src, const int* __restrict__ dst,
                               int* __restrict__ gcur, unsigned int* __restrict__ binned,
                               int e, int nbuk) {
    __shared__ int cnt[NBUK_MAX];
    __shared__ int pos[NBUK_MAX];
    __shared__ int gb[NBUK_MAX];
    __shared__ unsigned int sorted[FILL_EDGES];
    __shared__ unsigned short aux[FILL_EDGES];
    __shared__ int stmp[256];

    int t = threadIdx.x;
    int e0 = blockIdx.x * FILL_EDGES;
    int m = min(FILL_EDGES, e - e0);

    for (int i = t; i < nbuk; i += 256) cnt[i] = 0;
    __syncthreads();
    for (int i = t; i < m; i += 256) atomicAdd(&cnt[dst[e0 + i] >> NPB_SHIFT], 1);
    __syncthreads();

    // exclusive scan cnt -> pos (4 buckets per thread + block scan)
    int v[4], s = 0;
#pragma unroll
    for (int k = 0; k < 4; ++k) {
        int i = 4 * t + k;
        v[k] = (i < nbuk) ? cnt[i] : 0;
        s += v[k];
    }
    stmp[t] = s;
    __syncthreads();
    for (int off = 1; off < 256; off <<= 1) {
        int x = (t >= off) ? stmp[t - off] : 0;
        __syncthreads();
        stmp[t] += x;
        __syncthreads();
    }
    int run = stmp[t] - s;
#pragma unroll
    for (int k = 0; k < 4; ++k) {
        int i = 4 * t + k;
        if (i < nbuk) pos[i] = run;
        run += v[k];
    }
    __syncthreads();

    // scatter into LDS-sorted order (pos[b] advances from exclusive start)
    for (int i = t; i < m; i += 256) {
        int d = dst[e0 + i];
        int sv = src[e0 + i];
        int b = d >> NPB_SHIFT;
        int r = atomicAdd(&pos[b], 1);
        sorted[r] = ((unsigned int)(d & (NPB - 1)) << 17) | (unsigned int)sv;
        aux[r] = (unsigned short)b;
    }
    __syncthreads();

    // reserve global space per bucket (one atomic per nonzero bucket)
    for (int b = t; b < nbuk; b += 256) {
        int c = cnt[b];
        gb[b] = c ? atomicAdd(&gcur[b], c) : 0;
    }
    __syncthreads();

    // bulk copy: consecutive LDS idx -> consecutive global idx within runs
    for (int i = t; i < m; i += 256) {
        int b = aux[i];
        int start = pos[b] - cnt[b];   // pos[b] is now end offset
        binned[gb[b] + (i - start)] = sorted[i];
    }
}

// mqc[r][c] = (x[r]·W1[:,c]) * dinv[r], bf16
#define XLD 132
__global__ void gemm1_kernel(const float* __restrict__ x, const float* __restrict__ W1,
                             const float* __restrict__ dinv,
                             unsigned short* __restrict__ mqc, int n) {
    __shared__ float  Xl[32 * XLD];
    __shared__ float4 Wl4[DIN * 8];

    int t = threadIdx.x;
    for (int i = t; i < DIN * 8; i += 256) Wl4[i] = ((const float4*)W1)[i];

    int rb = blockIdx.x * 32;
    for (int i = t; i < 32 * 32; i += 256) {
        int rr = i >> 5, c4 = i & 31;
        int gr = rb + rr;
        float4 v = make_float4(0.f, 0.f, 0.f, 0.f);
        if (gr < n) v = ((const float4*)x)[(size_t)gr * 32 + c4];
        ((float4*)Xl)[rr * 33 + c4] = v;
    }
    __syncthreads();

    const int lane = t & 7;
    const int row  = t >> 3;
    const float* xrow = &Xl[row * XLD];
    float4 acc = make_float4(0.f, 0.f, 0.f, 0.f);
#pragma unroll
    for (int k = 0; k < DIN; ++k) {
        float xv = xrow[k];
        float4 w = Wl4[k * 8 + lane];
        acc.x += xv * w.x; acc.y += xv * w.y;
        acc.z += xv * w.z; acc.w += xv * w.w;
    }
    int r = rb + row;
    if (r < n) {
        float di = dinv[r];
        unsigned short* p = &mqc[(size_t)r * DH + 4 * lane];
        p[0] = f2bf(acc.x * di); p[1] = f2bf(acc.y * di);
        p[2] = f2bf(acc.z * di); p[3] = f2bf(acc.w * di);
    }
}

// one block per bucket: LDS fp32 accumulate neighbor messages, fuse
// ReLU + W2 transform, emit m2q.  halfwave (32 lanes) per edge, lane = dim.
__global__ void agg1_kernel(const int* __restrict__ gbase, const int* __restrict__ gcnt,
                            const unsigned int* __restrict__ binned,
                            const unsigned short* __restrict__ mqc,
                            const float* __restrict__ dinv,
                            const float* __restrict__ b1, const float* __restrict__ W2,
                            float2* __restrict__ m2q, int n) {
    __shared__ float acc[NPB * DH];   // 16 KB
    int t = threadIdx.x;
    int b = blockIdx.x;
    for (int i = t; i < NPB * DH; i += 256) acc[i] = 0.f;
    __syncthreads();

    const int beg = gbase[b];
    const int cntb = gcnt[b];
    const int lane = t & 31;
    const int half = t >> 5;     // 0..7

    for (int i0 = half * 32; i0 < cntb; i0 += 8 * 32) {
        int mm = min(32, cntb - i0);
        unsigned int ev = (i0 + lane < cntb) ? binned[beg + i0 + lane] : 0u;
        for (int u = 0; u < mm; ++u) {
            unsigned int entry = __shfl(ev, u, 32);
            int sv = (int)(entry & 0x1FFFFu);
            int dl = (int)(entry >> 17);
            float val = bf2f(mqc[(size_t)sv * DH + lane]);
            atomicAdd(&acc[dl * DH + lane], val);
        }
    }
    __syncthreads();

    int r0 = b << NPB_SHIFT;
    for (int rl = half; rl < NPB; rl += 8) {
        int r = r0 + rl;
        if (r >= n) break;
        float di = dinv[r];
        float a = acc[rl * DH + lane] + bf2f(mqc[(size_t)r * DH + lane]);
        float h = fmaxf(di * a + b1[lane], 0.0f);
        float p0 = h * W2[lane * DOUT + 0];
        float p1 = h * W2[lane * DOUT + 1];
#pragma unroll
        for (int off = 16; off > 0; off >>= 1) {
            p0 += __shfl_down(p0, off, 32);
            p1 += __shfl_down(p1, off, 32);
        }
        if (lane == 0) m2q[r] = make_float2(di * p0, di * p1);
    }
}

// one block per bucket: layer-2 aggregate + bias, write out directly
__global__ void agg2_kernel(const int* __restrict__ gbase, const int* __restrict__ gcnt,
                            const unsigned int* __restrict__ binned,
                            const float2* __restrict__ m2q,
                            const float* __restrict__ dinv, const float* __restrict__ b2,
                            float* __restrict__ out, int n) {
    __shared__ float acc0[NPB], acc1[NPB];
    int t = threadIdx.x;
    int b = blockIdx.x;
    for (int i = t; i < NPB; i += 256) { acc0[i] = 0.f; acc1[i] = 0.f; }
    __syncthreads();

    const int beg = gbase[b];
    const int cntb = gcnt[b];
    for (int i = t; i < cntb; i += 256) {
        unsigned int entry = binned[beg + i];
        int sv = (int)(entry & 0x1FFFFu);
        int dl = (int)(entry >> 17);
        float2 v = m2q[sv];
        atomicAdd(&acc0[dl], v.x);
        atomicAdd(&acc1[dl], v.y);
    }
    __syncthreads();

    int r0 = b << NPB_SHIFT;
    for (int rl = t; rl < NPB; rl += 256) {
        int r = r0 + rl;
        if (r < n) {
            float di = dinv[r];
            float2 self = m2q[r];
            out[(size_t)r * DOUT + 0] = di * (acc0[rl] + self.x) + b2[0];
            out[(size_t)r * DOUT + 1] = di * (acc1[rl] + self.y) + b2[1];
        }
    }
}

extern "C" void kernel_launch(void* const* d_in, const int* in_sizes, int n_in,
                              void* d_out, int out_size, void* d_ws, size_t ws_size,
                              hipStream_t stream) {
    const float* x  = (const float*)d_in[0];
    const int*   ei = (const int*)d_in[1];
    const float* W1 = (const float*)d_in[2];
    const float* b1 = (const float*)d_in[3];
    const float* W2 = (const float*)d_in[4];
    const float* b2 = (const float*)d_in[5];
    float* out = (float*)d_out;

    const int n = in_sizes[0] / DIN;
    const int e = in_sizes[1] / 2;
    const int* src = ei;
    const int* dst = ei + e;
    const int nbuk = (n + NPB - 1) >> NPB_SHIFT;   // 782 for n=100000

    char* ws = (char*)d_ws;
    int* deg      = (int*)ws;            ws += (size_t)n * 4;
    float* dinv   = (float*)ws;          ws += (size_t)n * 4;
    int* gcnt     = (int*)ws;            ws += NBUK_MAX * 4;
    int* gbase    = (int*)ws;            ws += NBUK_MAX * 4;
    int* gcur     = (int*)ws;            ws += NBUK_MAX * 4;
    unsigned int* binned = (unsigned int*)ws;  ws += (size_t)e * 4;
    unsigned short* mqc  = (unsigned short*)ws; ws += (size_t)n * DH * 2;
    float2* m2q   = (float2*)ws;

    const int B = 256;
    const int fill_blocks = (e + FILL_EDGES - 1) / FILL_EDGES;   // 391

    zero_kernel<<<(n + B - 1) / B, B, 0, stream>>>(deg, gcnt, n, nbuk);
    hist_kernel<<<fill_blocks, B, 0, stream>>>(dst, deg, gcnt, e, nbuk);
    dinv_kernel<<<(n + B - 1) / B, B, 0, stream>>>(deg, dinv, n);
    scan_kernel<<<1, B, 0, stream>>>(gcnt, gbase, gcur, nbuk);
    binfill_kernel<<<fill_blocks, B, 0, stream>>>(src, dst, gcur, binned, e, nbuk);
    gemm1_kernel<<<(n + 31) / 32, B, 0, stream>>>(x, W1, dinv, mqc, n);
    agg1_kernel<<<nbuk, B, 0, stream>>>(gbase, gcnt, binned, mqc, dinv, b1, W2, m2q, n);
    agg2_kernel<<<nbuk, B, 0, stream>>>(gbase, gcnt, binned, m2q, dinv, b2, out, n);
}